// Round 8
// baseline (647.047 us; speedup 1.0000x reference)
//
#include <hip/hip_runtime.h>
#include <math.h>

#define Hc   128
#define Bc   512
#define Tc   64
#define NXc  518
#define NCELL (518*518)
#define NEV  (Bc*Tc)            // 32768 events
#define SWc  2

// ---------------- precompute kernels ----------------

__global__ void k_build(const float* __restrict__ feat, int* __restrict__ head,
                        int* __restrict__ nxt, int* __restrict__ cellxy) {
    int gid = blockIdx.x * 256 + threadIdx.x;
    if (gid >= NEV) return;
    int b = gid >> 6, t = gid & 63;
    int base = (b * Tc + t) * 4;
    int gx = (int)feat[base + 2] + SWc;
    int gy = (int)feat[base + 3] + SWc;
    gx = min(max(gx, 0), NXc - 1);
    gy = min(max(gy, 0), NXc - 1);
    int cell = gx * NXc + gy;
    int e = t * Bc + b;
    cellxy[e] = (gx << 16) | gy;
    int old = atomicExch(&head[cell], e);
    nxt[e] = old;
}

__global__ void k_resolve(const int* __restrict__ head, const int* __restrict__ nxt,
                          const int* __restrict__ cellxy, int* __restrict__ dep) {
    int gid = blockIdx.x * 256 + threadIdx.x;
    if (gid >= NEV * 25) return;
    int r = gid / 25, k = gid - r * 25;
    int t = r & 63, b = r >> 6;
    int e0 = t * Bc + b;
    int xy = cellxy[e0];
    int gx = xy >> 16, gy = xy & 0xffff;
    int cx = gx + (k / 5) - SWc, cy = gy + (k % 5) - SWc;
    cx = min(max(cx, 0), NXc - 1);
    cy = min(max(cy, 0), NXc - 1);
    int cell = cx * NXc + cy;
    int best = -1;
    for (int e = head[cell]; e >= 0; e = nxt[e])
        if ((e >> 9) < t && e > best) best = e;
    dep[r * 25 + k] = best;
}

// ---------------- fast math ----------------

#define LOG2E 1.4426950408889634f
__device__ __forceinline__ float fexp(float x)  { return __builtin_amdgcn_exp2f(x * LOG2E); }
__device__ __forceinline__ float fsig(float x)  { return __builtin_amdgcn_rcpf(1.f + fexp(-x)); }
__device__ __forceinline__ float ftanh(float x) { return 1.f - 2.f * __builtin_amdgcn_rcpf(1.f + fexp(2.f * x)); }

// Raw barrier: waits LDS only (lgkmcnt(0)); global ops stay in flight.
__device__ __forceinline__ void barlds() {
    asm volatile("" ::: "memory");
    __builtin_amdgcn_s_waitcnt(0xC07F);   // vmcnt=63, expcnt=7, lgkmcnt=0
    __builtin_amdgcn_s_barrier();
    asm volatile("" ::: "memory");
}

__device__ __forceinline__ unsigned long long gload(const unsigned long long* p) {
    return __hip_atomic_load(p, __ATOMIC_RELAXED, __HIP_MEMORY_SCOPE_AGENT);
}

// ---------------- main persistent dataflow kernel ----------------

#define WSTRIDE 257
#define L_WOUT  (128 * WSTRIDE)
constexpr int LDS_FLOATS = L_WOUT + 256 + 1024 + 256 + 256 + 64 + 2048 + 512 + 16 + 128 + 64;
constexpr int LDS_BYTES  = LDS_FLOATS * 4;   // ~150 KB <= 160 KiB

__global__ void
__attribute__((amdgpu_flat_work_group_size(1024, 1024)))
__attribute__((amdgpu_waves_per_eu(4, 4)))
step_main(const float* __restrict__ feat, const float* __restrict__ Wih,
          const float* __restrict__ bih,  const float* __restrict__ Whh,
          const float* __restrict__ bhh,  const float* __restrict__ Wout,
          const float* __restrict__ bout, const int*   __restrict__ seq,
          const int*   __restrict__ dep,  unsigned long long* __restrict__ vbuf,
          float* __restrict__ dout) {
    extern __shared__ float lds[];
    float* WoutL = lds;                 // 128*257
    float* hid   = WoutL + L_WOUT;      // 2*128
    float* g     = hid   + 256;         // 2*512 gate pre-acts (persist through step)
    float* gin   = g     + 1024;        // 2*128
    float* ctr   = gin   + 256;         // 2*128
    float* scor  = ctr   + 256;         // 2*32
    float* pmix  = scor  + 64;          // 16*128 W_out partials
    float* catL  = pmix  + 2048;        // 2*256 cat=[mix,q]
    float* fxy   = catL  + 512;         // 2 parities * 8
    float* boutL = fxy   + 16;          // 128
    int*   depv  = (int*)(boutL + 128); // 2*25 (+pad), deps for t+1

    const int tid  = threadIdx.x;       // 0..1023
    const int blk  = blockIdx.x;
    const int lane = tid & 63;
    const int w    = tid >> 6;          // wave 0..15
    const int wj   = w >> 3;            // chain of this wave
    const int ww   = w & 7;             // wave-within-chain

    // ---- persistent register weights: HALF a W_hh row (64 VGPRs) ----
    const int o    = tid >> 1;
    const int half = tid & 1;
    float4 wr[16];                      // statically indexed only (rule #20)
    {
        const float4* wp = (const float4*)(Whh + (size_t)o * Hc + half * 64);
        #pragma unroll
        for (int i = 0; i < 16; ++i) wr[i] = wp[i];
    }
    const float bihr = bih[o], bhhr = bhh[o];
    const float wih0 = Wih[o * 2 + 0], wih1 = Wih[o * 2 + 1];
    const int chunk = o >> 7;

    for (int i = tid; i < 128 * 256; i += 1024)
        WoutL[(i >> 8) * WSTRIDE + (i & 255)] = Wout[i];
    if (tid < 128) boutL[tid] = bout[tid];
    if (tid < 256) hid[tid] = 0.f;
    if (tid < 8) { int j = tid >> 2, c = tid & 3;
                   fxy[tid] = feat[((size_t)(blk * 2 + j) * Tc + 0) * 4 + c]; }
    const int s0 = max(seq[blk * 2 + 0], 1) - 1;
    const int s1 = max(seq[blk * 2 + 1], 1) - 1;
    __syncthreads();

    const float NEG_INF = -__builtin_inff();

    // per-wave dep state (t=0 has no deps by construction)
    int ev[4]; bool pend[4]; float2 valk[4];
    #pragma unroll
    for (int kk = 0; kk < 4; ++kk) { ev[kk] = -1; pend[kk] = false; valk[kk] = make_float2(0.f, 0.f); }

    for (int t = 0; t < Tc; ++t) {
        const float* fx = fxy + (t & 1) * 8;

        // ======== A: gh GEMV (W_hh in regs, hid LDS broadcast) + dep/fxy prefetch ========
        float acc0j, acc1j;
        {
            const float4* hp0 = (const float4*)(hid + half * 64);
            const float4* hp1 = (const float4*)(hid + 128 + half * 64);
            float a0 = 0.f, a1 = 0.f, a2 = 0.f, a3 = 0.f;
            float b0 = 0.f, b1 = 0.f, b2 = 0.f, b3 = 0.f;
            #pragma unroll
            for (int i = 0; i < 16; ++i) {
                float4 w4 = wr[i];
                float4 h0 = hp0[i], h1 = hp1[i];
                a0 = fmaf(w4.x, h0.x, a0); a1 = fmaf(w4.y, h0.y, a1);
                a2 = fmaf(w4.z, h0.z, a2); a3 = fmaf(w4.w, h0.w, a3);
                b0 = fmaf(w4.x, h1.x, b0); b1 = fmaf(w4.y, h1.y, b1);
                b2 = fmaf(w4.z, h1.z, b2); b3 = fmaf(w4.w, h1.w, b3);
            }
            acc0j = (a0 + a1) + (a2 + a3);
            acc1j = (b0 + b1) + (b2 + b3);
        }
        acc0j += __shfl_xor(acc0j, 1, 64);
        acc1j += __shfl_xor(acc1j, 1, 64);
        if (half == 0) {
            float gi0 = fmaf(wih0, fx[0], wih1 * fx[1]);
            float gi1 = fmaf(wih0, fx[4], wih1 * fx[5]);
            g[o]       = acc0j + bhhr + ((chunk == 2) ? 0.f : (gi0 + bihr));
            g[512 + o] = acc1j + bhhr + ((chunk == 2) ? 0.f : (gi1 + bihr));
            if (chunk == 2) { gin[o & 127] = gi0 + bihr; gin[128 + (o & 127)] = gi1 + bihr; }
        }
        if (tid >= 512 && tid < 562 && t + 1 < Tc) {   // deps for t+1
            int idx = tid - 512;
            int j = (idx >= 25), k = idx - j * 25;
            depv[idx] = dep[(((size_t)(blk * 2 + j)) * Tc + (t + 1)) * 25 + k];
        }
        if (tid >= 960 && tid < 968 && t + 1 < Tc) {   // fxy for t+1
            int idx = tid - 960, j = idx >> 2, c = idx & 3;
            fxy[((t + 1) & 1) * 8 + idx] =
                feat[((size_t)(blk * 2 + j) * Tc + (t + 1)) * 4 + c];
        }
        barlds();

        // ======== BC: per-wave gates + spin (rare) + ctr + scores ========
        float q0, q1;
        {
            float gr0 = g[wj * 512 + 2 * lane],       gr1 = g[wj * 512 + 2 * lane + 1];
            float gn0 = g[wj * 512 + 256 + 2 * lane], gn1 = g[wj * 512 + 256 + 2 * lane + 1];
            float gi0 = gin[wj * 128 + 2 * lane],     gi1 = gin[wj * 128 + 2 * lane + 1];
            q0 = ftanh(gi0 + fsig(gr0) * gn0);
            q1 = ftanh(gi1 + fsig(gr1) * gn1);
        }
        if (ww == 0) { catL[wj * 256 + 128 + 2 * lane] = q0;
                       catL[wj * 256 + 128 + 2 * lane + 1] = q1; }
        if (ww == 1) { catL[wj * 256 + 2 * lane] = 0.f;
                       catL[wj * 256 + 2 * lane + 1] = 0.f; }
        while (__any(pend[0] | pend[1] | pend[2] | pend[3])) {
            #pragma unroll
            for (int kk = 0; kk < 4; ++kk) {
                if (pend[kk]) {
                    unsigned exp = (unsigned)((ev[kk] >> 9) + 1);
                    unsigned long long r0 = gload(vbuf + (size_t)ev[kk] * 128 + 2 * lane);
                    unsigned long long r1 = gload(vbuf + (size_t)ev[kk] * 128 + 2 * lane + 1);
                    if ((unsigned)(r0 >> 32) == exp && (unsigned)(r1 >> 32) == exp) {
                        valk[kk] = make_float2(__uint_as_float((unsigned)r0),
                                               __uint_as_float((unsigned)r1));
                        pend[kk] = false;
                    }
                }
            }
            if (__any(pend[0] | pend[1] | pend[2] | pend[3]))
                __builtin_amdgcn_s_sleep(1);
        }
        if (ww == 4) {   // owns k=12 (kk=1): center context
            float cx = (ev[1] >= 0) ? valk[1].x : 0.f;
            float cy = (ev[1] >= 0) ? valk[1].y : 0.f;
            ctr[wj * 128 + 2 * lane]     = cx;
            ctr[wj * 128 + 2 * lane + 1] = cy;
        }
        #pragma unroll
        for (int kk = 0; kk < 4; ++kk) {
            int k = ww + 8 * kk;
            if (k < 25) {
                float sc;
                if (ev[kk] >= 0) {
                    float d = fmaf(valk[kk].x, q0, valk[kk].y * q1);
                    #pragma unroll
                    for (int m = 1; m < 64; m <<= 1) d += __shfl_xor(d, m, 64);
                    sc = (d == 0.f) ? NEG_INF : d;
                } else sc = NEG_INF;
                if (lane == 0) scor[wj * 32 + k] = sc;
            }
        }
        barlds();

        // ======== D: per-wave softmax + mix via LDS float atomics ========
        {
            int k2 = lane & 31;
            float v = (k2 < 25) ? scor[wj * 32 + k2] : NEG_INF;
            float m = v;
            #pragma unroll
            for (int mm = 1; mm < 32; mm <<= 1) m = fmaxf(m, __shfl_xor(m, mm, 64));
            float a = 0.f;
            if (m != NEG_INF) {
                float p = (v == NEG_INF) ? 0.f : fexp(v - m);
                float s = p;
                #pragma unroll
                for (int mm = 1; mm < 32; mm <<= 1) s += __shfl_xor(s, mm, 64);
                a = p / s;
            }
            if ((ev[0] >= 0) || (ev[1] >= 0) || (ev[2] >= 0) || (ev[3] >= 0)) {
                float pm0 = 0.f, pm1 = 0.f;
                #pragma unroll
                for (int kk = 0; kk < 4; ++kk) {
                    int k = ww + 8 * kk;
                    if (k < 25 && ev[kk] >= 0) {
                        float ak = __shfl(a, k, 64);
                        pm0 = fmaf(ak, valk[kk].x, pm0);
                        pm1 = fmaf(ak, valk[kk].y, pm1);
                    }
                }
                atomicAdd(&catL[wj * 256 + 2 * lane],     pm0);
                atomicAdd(&catL[wj * 256 + 2 * lane + 1], pm1);
            }
        }
        barlds();

        // ======== E2: dep tag-check loads (t+1) ; W_out dots ; evaluate tags ========
        unsigned long long r0s[4], r1s[4];
        #pragma unroll
        for (int kk = 0; kk < 4; ++kk) {
            int k = ww + 8 * kk;
            int e = -1;
            if (t + 1 < Tc && k < 25) e = depv[wj * 25 + k];
            ev[kk] = e; r0s[kk] = 0; r1s[kk] = 0;
            if (e >= 0) {
                r0s[kk] = gload(vbuf + (size_t)e * 128 + 2 * lane);
                r1s[kk] = gload(vbuf + (size_t)e * 128 + 2 * lane + 1);
            }
        }
        {
            int oo = tid & 127, rep = tid >> 7;
            const float* wrow = WoutL + oo * WSTRIDE + rep * 32;
            const float* c0   = catL + rep * 32;
            const float* c1   = catL + 256 + rep * 32;
            float acc0 = 0.f, acc1 = 0.f;
            #pragma unroll
            for (int i = 0; i < 32; ++i) {
                float wv = wrow[i];
                acc0 = fmaf(wv, c0[i], acc0);
                acc1 = fmaf(wv, c1[i], acc1);
            }
            pmix[rep * 128 + oo]       = acc0;
            pmix[(8 + rep) * 128 + oo] = acc1;
        }
        #pragma unroll
        for (int kk = 0; kk < 4; ++kk) {
            pend[kk] = false; valk[kk] = make_float2(0.f, 0.f);
            if (ev[kk] >= 0) {
                unsigned exp = (unsigned)((ev[kk] >> 9) + 1);
                bool ok = ((unsigned)(r0s[kk] >> 32) == exp) &&
                          ((unsigned)(r1s[kk] >> 32) == exp);
                valk[kk] = make_float2(__uint_as_float((unsigned)r0s[kk]),
                                       __uint_as_float((unsigned)r1s[kk]));
                pend[kk] = !ok;
            }
        }
        barlds();

        // ======== E3: epilogue (gates recomputed from g) + tagged vbuf publish ========
        if (tid < 256) {
            int j = tid >> 7, h = tid & 127;
            float tot = boutL[h];
            #pragma unroll
            for (int p = 0; p < 8; ++p) tot += pmix[(j * 8 + p) * 128 + h];
            float at = ftanh(tot);
            float gr = g[j * 512 + h],       gu = g[j * 512 + 128 + h];
            float gn = g[j * 512 + 256 + h], gs = g[j * 512 + 384 + h];
            float rr = fsig(gr), uu = fsig(gu), ss = fsig(gs);
            float nn = ftanh(gin[j * 128 + h] + rr * gn);
            float hv = hid[j * 128 + h];
            float curr = fmaf(ss, at, nn);
            float outv = curr + uu * (hv - curr);
            hid[j * 128 + h] = outv;
            if (t < Tc - 1) {   // t=63 never consumed
                float upd = fmaf(ss, ctr[j * 128 + h], (1.f - ss) * outv);
                int e = t * Bc + blk * 2 + j;
                unsigned long long payload =
                    ((unsigned long long)(unsigned)(t + 1) << 32) |
                    (unsigned long long)__float_as_uint(upd);
                __hip_atomic_store(vbuf + (size_t)e * 128 + h, payload,
                                   __ATOMIC_RELAXED, __HIP_MEMORY_SCOPE_AGENT);
            }
            int sj = (j == 0) ? s0 : s1;
            if (sj == t) dout[(size_t)(blk * 2 + j) * Hc + h] = outv;
        }
        barlds();
    }
}

// ---------------- host launch ----------------

extern "C" void kernel_launch(void* const* d_in, const int* in_sizes, int n_in,
                              void* d_out, int out_size, void* d_ws, size_t ws_size,
                              hipStream_t stream) {
    const float* feat = (const float*)d_in[0];
    const float* Wih  = (const float*)d_in[1];
    const float* bih  = (const float*)d_in[2];
    const float* Whh  = (const float*)d_in[3];
    const float* bhh  = (const float*)d_in[4];
    const float* Wout = (const float*)d_in[5];
    const float* bout = (const float*)d_in[6];
    const int*   seq  = (const int*)d_in[7];

    char* ws = (char*)d_ws;
    size_t off = 0;
    auto carve = [&](size_t bytes) { char* p = ws + off; off += (bytes + 511) & ~(size_t)511; return p; };
    unsigned long long* vbuf = (unsigned long long*)carve((size_t)NEV * Hc * 8);  // 33.5 MB tagged
    int* head   = (int*)carve((size_t)NCELL * 4);
    int* nxt    = (int*)carve((size_t)NEV * 4);
    int* cellxy = (int*)carve((size_t)NEV * 4);
    int* dep    = (int*)carve((size_t)NEV * 25 * 4);

    hipMemsetAsync(vbuf, 0, (size_t)NEV * Hc * 8, stream);   // reset epoch tags
    hipMemsetAsync(head, 0xFF, (size_t)NCELL * 4, stream);

    k_build<<<(NEV + 255) / 256, 256, 0, stream>>>(feat, head, nxt, cellxy);
    k_resolve<<<(NEV * 25 + 255) / 256, 256, 0, stream>>>(head, nxt, cellxy, dep);

    hipFuncSetAttribute((const void*)step_main,
                        hipFuncAttributeMaxDynamicSharedMemorySize, LDS_BYTES);
    step_main<<<256, 1024, LDS_BYTES, stream>>>(feat, Wih, bih, Whh, bhh, Wout, bout,
                                                seq, dep, vbuf, (float*)d_out);
}

// Round 9
// 553.163 us; speedup vs baseline: 1.1697x; 1.1697x over previous
//
#include <hip/hip_runtime.h>
#include <math.h>

#define Hc   128
#define Bc   512
#define Tc   64
#define NXc  518
#define NCELL (518*518)
#define NEV  (Bc*Tc)            // 32768 events
#define SWc  2

// ---------------- precompute kernels ----------------

__global__ void k_build(const float* __restrict__ feat, int* __restrict__ head,
                        int* __restrict__ nxt, int* __restrict__ cellxy) {
    int gid = blockIdx.x * 256 + threadIdx.x;
    if (gid >= NEV) return;
    int b = gid >> 6, t = gid & 63;
    int base = (b * Tc + t) * 4;
    int gx = (int)feat[base + 2] + SWc;
    int gy = (int)feat[base + 3] + SWc;
    gx = min(max(gx, 0), NXc - 1);
    gy = min(max(gy, 0), NXc - 1);
    int cell = gx * NXc + gy;
    int e = t * Bc + b;
    cellxy[e] = (gx << 16) | gy;
    int old = atomicExch(&head[cell], e);
    nxt[e] = old;
}

__global__ void k_resolve(const int* __restrict__ head, const int* __restrict__ nxt,
                          const int* __restrict__ cellxy, int* __restrict__ dep) {
    int gid = blockIdx.x * 256 + threadIdx.x;
    if (gid >= NEV * 25) return;
    int r = gid / 25, k = gid - r * 25;
    int t = r & 63, b = r >> 6;
    int e0 = t * Bc + b;
    int xy = cellxy[e0];
    int gx = xy >> 16, gy = xy & 0xffff;
    int cx = gx + (k / 5) - SWc, cy = gy + (k % 5) - SWc;
    cx = min(max(cx, 0), NXc - 1);
    cy = min(max(cy, 0), NXc - 1);
    int cell = cx * NXc + cy;
    int best = -1;
    for (int e = head[cell]; e >= 0; e = nxt[e])
        if ((e >> 9) < t && e > best) best = e;
    dep[r * 25 + k] = best;
}

// ---------------- fast math ----------------

#define LOG2E 1.4426950408889634f
__device__ __forceinline__ float fexp(float x)  { return __builtin_amdgcn_exp2f(x * LOG2E); }
__device__ __forceinline__ float fsig(float x)  { return __builtin_amdgcn_rcpf(1.f + fexp(-x)); }
__device__ __forceinline__ float ftanh(float x) { return 1.f - 2.f * __builtin_amdgcn_rcpf(1.f + fexp(2.f * x)); }

// LDS-only barrier: waits lgkmcnt(0), leaves global ops in flight.
__device__ __forceinline__ void barlds() {
    asm volatile("" ::: "memory");
    __builtin_amdgcn_s_waitcnt(0xC07F);   // vmcnt=63, expcnt=7, lgkmcnt=0
    __builtin_amdgcn_s_barrier();
    asm volatile("" ::: "memory");
}

// ---------------- main persistent dataflow kernel ----------------

// LDS floats: WoutL(f4-swizzled 128x64xf4) + the step buffers
constexpr int LDS_FLOATS = 32768 + 256 + 1024 + 256 + 256 + 256 + 256 + 256 + 64 + 2048 + 16 + 128 + 64;
constexpr int LDS_BYTES  = LDS_FLOATS * 4;   // 150,592 B <= 160 KiB

__global__ void
__attribute__((amdgpu_flat_work_group_size(1024, 1024)))
__attribute__((amdgpu_waves_per_eu(4, 4)))
step_main(const float* __restrict__ feat, const float* __restrict__ Wih,
          const float* __restrict__ bih,  const float* __restrict__ Whh,
          const float* __restrict__ bhh,  const float* __restrict__ Wout,
          const float* __restrict__ bout, const int*   __restrict__ seq,
          const int*   __restrict__ dep,  float* __restrict__ vbuf,
          unsigned*    __restrict__ flags, float* __restrict__ dout) {
    extern __shared__ float lds[];
    float* WoutL = lds;                 // 128 rows x 64 float4, XOR-swizzled
    float* hid   = WoutL + 32768;       // 2*128
    float* g     = hid   + 256;         // 2*512 gate pre-acts; reused as cat[2][256]
    float* gin   = g     + 1024;        // 2*128
    float* qv    = gin   + 256;
    float* ug    = qv    + 256;
    float* sg    = ug    + 256;
    float* ctr   = sg    + 256;
    float* scor  = ctr   + 256;         // 2*32
    float* pmix  = scor  + 64;          // 16 rows * 128
    float* fxy   = pmix  + 2048;        // 2 parities * 8
    float* boutL = fxy   + 16;          // 128
    int*   depv  = (int*)(boutL + 128); // 2*25 (+pad)

    const int tid  = threadIdx.x;       // 0..1023
    const int blk  = blockIdx.x;
    const int lane = tid & 63;
    const int w    = tid >> 6;          // wave 0..15
    const int wj   = w >> 3;            // chain of this wave
    const int ww   = w & 7;             // wave-within-chain

    // ---- persistent register weights: HALF a W_hh row (64 VGPRs), PINNED ----
    const int o    = tid >> 1;
    const int half = tid & 1;
    float4 wr[16];                      // statically indexed only (rule #20)
    {
        const float4* wp = (const float4*)(Whh + (size_t)o * Hc + half * 64);
        #pragma unroll
        for (int i = 0; i < 16; ++i) wr[i] = wp[i];
    }
    // Opaque-value pin: forbids rematerialization-by-reload (the R6 L2 stall).
    #pragma unroll
    for (int i = 0; i < 16; ++i)
        asm volatile("" : "+v"(wr[i].x), "+v"(wr[i].y), "+v"(wr[i].z), "+v"(wr[i].w));

    const float bihr = bih[o], bhhr = bhh[o];
    const float wih0 = Wih[o * 2 + 0], wih1 = Wih[o * 2 + 1];
    const int chunk = o >> 7;

    // stage W_out into swizzled-f4 LDS: logical (r, c4) -> phys f4 = r*64 + (c4 ^ (r&7))
    for (int i = tid; i < 128 * 256; i += 1024) {
        int r = i >> 8, c = i & 255;
        int c4 = c >> 2, cc = c & 3;
        WoutL[(r * 64 + (c4 ^ (r & 7))) * 4 + cc] = Wout[i];
    }
    if (tid < 128) boutL[tid] = bout[tid];
    if (tid < 256) hid[tid] = 0.f;
    if (tid < 8) { int j = tid >> 2, c = tid & 3;
                   fxy[tid] = feat[((size_t)(blk * 2 + j) * Tc + 0) * 4 + c]; }
    const int s0 = max(seq[blk * 2 + 0], 1) - 1;
    const int s1 = max(seq[blk * 2 + 1], 1) - 1;
    __syncthreads();

    const float NEG_INF = -__builtin_inff();

    for (int t = 0; t < Tc; ++t) {
        const float* fx = fxy + (t & 1) * 8;

        // ---- P1: half-row gh dots (wr in regs) + dep/fxy prefetch ----
        float acc0j, acc1j;
        {
            const float4* hp0 = (const float4*)(hid + half * 64);
            const float4* hp1 = (const float4*)(hid + 128 + half * 64);
            float a0 = 0.f, a1 = 0.f, a2 = 0.f, a3 = 0.f;
            float b0 = 0.f, b1 = 0.f, b2 = 0.f, b3 = 0.f;
            #pragma unroll
            for (int i = 0; i < 16; ++i) {
                float4 w4 = wr[i];
                float4 h0 = hp0[i], h1 = hp1[i];
                a0 = fmaf(w4.x, h0.x, a0); a1 = fmaf(w4.y, h0.y, a1);
                a2 = fmaf(w4.z, h0.z, a2); a3 = fmaf(w4.w, h0.w, a3);
                b0 = fmaf(w4.x, h1.x, b0); b1 = fmaf(w4.y, h1.y, b1);
                b2 = fmaf(w4.z, h1.z, b2); b3 = fmaf(w4.w, h1.w, b3);
            }
            acc0j = (a0 + a1) + (a2 + a3);
            acc1j = (b0 + b1) + (b2 + b3);
        }
        acc0j += __shfl_xor(acc0j, 1, 64);
        acc1j += __shfl_xor(acc1j, 1, 64);
        if (half == 0) {
            float gi0 = fmaf(wih0, fx[0], wih1 * fx[1]);
            float gi1 = fmaf(wih0, fx[4], wih1 * fx[5]);
            g[o]       = acc0j + bhhr + ((chunk == 2) ? 0.f : (gi0 + bihr));
            g[512 + o] = acc1j + bhhr + ((chunk == 2) ? 0.f : (gi1 + bihr));
            if (chunk == 2) { gin[o & 127] = gi0 + bihr; gin[128 + (o & 127)] = gi1 + bihr; }
        }
        if (tid >= 512 && tid < 562) {
            int idx = tid - 512;
            int j = (idx >= 25), k = idx - j * 25;
            depv[idx] = dep[(((size_t)(blk * 2 + j)) * Tc + t) * 25 + k];
        }
        if (tid >= 960 && tid < 968 && t + 1 < Tc) {
            int idx = tid - 960, j = idx >> 2, c = idx & 3;
            fxy[((t + 1) & 1) * 8 + idx] =
                feat[((size_t)(blk * 2 + j) * Tc + (t + 1)) * 4 + c];
        }
        barlds();

        // ---- P2: gates (tid<256) + wave-parallel spin (1 dep per lane) ----
        if (tid < 256) {
            int j = tid >> 7, h = tid & 127;
            float gr = g[j * 512 + h],       gu = g[j * 512 + 128 + h];
            float gn = g[j * 512 + 256 + h], gs = g[j * 512 + 384 + h];
            float rr = fsig(gr), uu = fsig(gu), ss = fsig(gs);
            float nn = ftanh(gin[j * 128 + h] + rr * gn);
            qv[j * 128 + h] = nn; ug[j * 128 + h] = uu; sg[j * 128 + h] = ss;
            ctr[j * 128 + h] = 0.f;
        }
        {
            int e = (lane < 25) ? depv[wj * 25 + lane] : -1;
            bool pend = (e >= 0);
            if (pend && __hip_atomic_load(&flags[e], __ATOMIC_RELAXED,
                                          __HIP_MEMORY_SCOPE_AGENT) != 0u)
                pend = false;
            while (__any(pend)) {
                __builtin_amdgcn_s_sleep(1);
                if (pend && __hip_atomic_load(&flags[e], __ATOMIC_RELAXED,
                                              __HIP_MEMORY_SCOPE_AGENT) != 0u)
                    pend = false;
            }
            asm volatile("" ::: "memory");   // vbuf loads stay after the spin
        }
        barlds();

        // ---- P4: gather (cached; flag-gated write-once lines) + scores ----
        const float q0 = qv[wj * 128 + 2 * lane];
        const float q1 = qv[wj * 128 + 2 * lane + 1];
        #pragma unroll
        for (int kk = 0; kk < 4; ++kk) {
            int k = ww + 8 * kk;
            if (k < 25) {
                int e = depv[wj * 25 + k];
                float sc;
                if (e >= 0) {
                    float2 v = *(const float2*)(vbuf + (size_t)e * Hc + 2 * lane);
                    float d = fmaf(v.x, q0, v.y * q1);
                    #pragma unroll
                    for (int m = 1; m < 64; m <<= 1) d += __shfl_xor(d, m, 64);
                    sc = (d == 0.f) ? NEG_INF : d;
                    if (k == 12) { ctr[wj * 128 + 2 * lane]     = v.x;
                                   ctr[wj * 128 + 2 * lane + 1] = v.y; }
                } else sc = NEG_INF;
                if (lane == 0) scor[wj * 32 + k] = sc;
            }
        }
        barlds();

        // ---- P56: per-wave softmax + mix partials (vbuf re-read L1-hot) ----
        {
            int k2 = lane & 31;
            float v = (k2 < 25) ? scor[wj * 32 + k2] : NEG_INF;
            float m = v;
            #pragma unroll
            for (int mm = 1; mm < 32; mm <<= 1) m = fmaxf(m, __shfl_xor(m, mm, 64));
            float a = 0.f;
            if (m != NEG_INF) {
                float p = (v == NEG_INF) ? 0.f : fexp(v - m);
                float s = p;
                #pragma unroll
                for (int mm = 1; mm < 32; mm <<= 1) s += __shfl_xor(s, mm, 64);
                a = p / s;
            }
            float pm0 = 0.f, pm1 = 0.f;
            #pragma unroll
            for (int kk = 0; kk < 4; ++kk) {
                int k = ww + 8 * kk;
                if (k < 25) {
                    int e = depv[wj * 25 + k];
                    if (e >= 0) {
                        float ak = __shfl(a, k, 64);
                        float2 v = *(const float2*)(vbuf + (size_t)e * Hc + 2 * lane);
                        pm0 = fmaf(ak, v.x, pm0);
                        pm1 = fmaf(ak, v.y, pm1);
                    }
                }
            }
            *(float2*)&pmix[(wj * 8 + ww) * 128 + 2 * lane] = make_float2(pm0, pm1);
        }
        barlds();

        // ---- P7a: cat = [mix, q] into g ----
        if (tid < 256) {
            int j = tid >> 7, h = tid & 127;
            float mix = 0.f;
            #pragma unroll
            for (int p = 0; p < 8; ++p) mix += pmix[(j * 8 + p) * 128 + h];
            g[j * 512 + h] = mix;
            g[j * 512 + 128 + h] = qv[j * 128 + h];
        }
        barlds();

        // ---- P7b: W_out dots — swizzled b128 weights + b128 uniform cat ----
        {
            int oo = tid & 127, rep = tid >> 7;
            const float4* W4  = (const float4*)WoutL;
            const float4* c04 = (const float4*)(g + rep * 32);
            const float4* c14 = (const float4*)(g + 512 + rep * 32);
            float acc0 = 0.f, acc1 = 0.f;
            #pragma unroll
            for (int i = 0; i < 8; ++i) {
                float4 wv = W4[oo * 64 + ((rep * 8 + i) ^ (oo & 7))];
                float4 c0 = c04[i], c1 = c14[i];
                acc0 = fmaf(wv.x, c0.x, fmaf(wv.y, c0.y, fmaf(wv.z, c0.z, fmaf(wv.w, c0.w, acc0))));
                acc1 = fmaf(wv.x, c1.x, fmaf(wv.y, c1.y, fmaf(wv.z, c1.z, fmaf(wv.w, c1.w, acc1))));
            }
            pmix[rep * 128 + oo]       = acc0;
            pmix[(8 + rep) * 128 + oo] = acc1;
        }
        barlds();

        // ---- P7c: combine + epilogue + vbuf/dout stores ----
        if (tid < 256) {
            int j = tid >> 7, h = tid & 127;
            float tot = boutL[h];
            #pragma unroll
            for (int p = 0; p < 8; ++p) tot += pmix[(j * 8 + p) * 128 + h];
            float at = ftanh(tot);
            float n  = qv[j * 128 + h], uu = ug[j * 128 + h];
            float ss = sg[j * 128 + h], hv = hid[j * 128 + h];
            float curr = fmaf(ss, at, n);
            float outv = curr + uu * (hv - curr);
            hid[j * 128 + h] = outv;
            float upd = fmaf(ss, ctr[j * 128 + h], (1.f - ss) * outv);
            __hip_atomic_store(&vbuf[((size_t)(t * Bc + blk * 2 + j)) * Hc + h],
                               upd, __ATOMIC_RELAXED, __HIP_MEMORY_SCOPE_AGENT);
            int sj = (j == 0) ? s0 : s1;
            if (sj == t) dout[(size_t)(blk * 2 + j) * Hc + h] = outv;
        }
        __syncthreads();   // full drain: vbuf stores device-visible before flags
        if (tid == 0 || tid == 128) {
            int j = tid >> 7;
            __hip_atomic_store(&flags[t * Bc + blk * 2 + j], 1u,
                               __ATOMIC_RELAXED, __HIP_MEMORY_SCOPE_AGENT);
        }
    }
}

// ---------------- host launch ----------------

extern "C" void kernel_launch(void* const* d_in, const int* in_sizes, int n_in,
                              void* d_out, int out_size, void* d_ws, size_t ws_size,
                              hipStream_t stream) {
    const float* feat = (const float*)d_in[0];
    const float* Wih  = (const float*)d_in[1];
    const float* bih  = (const float*)d_in[2];
    const float* Whh  = (const float*)d_in[3];
    const float* bhh  = (const float*)d_in[4];
    const float* Wout = (const float*)d_in[5];
    const float* bout = (const float*)d_in[6];
    const int*   seq  = (const int*)d_in[7];

    char* ws = (char*)d_ws;
    size_t off = 0;
    auto carve = [&](size_t bytes) { char* p = ws + off; off += (bytes + 511) & ~(size_t)511; return p; };
    float*    vbuf   = (float*)   carve((size_t)NEV * Hc * 4);
    int*      head   = (int*)     carve((size_t)NCELL * 4);
    int*      nxt    = (int*)     carve((size_t)NEV * 4);
    int*      cellxy = (int*)     carve((size_t)NEV * 4);
    int*      dep    = (int*)     carve((size_t)NEV * 25 * 4);
    unsigned* flags  = (unsigned*)carve((size_t)NEV * 4);

    hipMemsetAsync(head, 0xFF, (size_t)NCELL * 4, stream);
    hipMemsetAsync(flags, 0, (size_t)NEV * 4, stream);

    k_build<<<(NEV + 255) / 256, 256, 0, stream>>>(feat, head, nxt, cellxy);
    k_resolve<<<(NEV * 25 + 255) / 256, 256, 0, stream>>>(head, nxt, cellxy, dep);

    hipFuncSetAttribute((const void*)step_main,
                        hipFuncAttributeMaxDynamicSharedMemorySize, LDS_BYTES);
    step_main<<<256, 1024, LDS_BYTES, stream>>>(feat, Wih, bih, Whh, bhh, Wout, bout,
                                                seq, dep, vbuf, flags, (float*)d_out);
}

// Round 10
// 515.722 us; speedup vs baseline: 1.2546x; 1.0726x over previous
//
#include <hip/hip_runtime.h>
#include <hip/hip_fp16.h>
#include <math.h>

#define Hc   128
#define Bc   512
#define Tc   64
#define NXc  518
#define NCELL (518*518)
#define NEV  (Bc*Tc)            // 32768 events
#define SWc  2

// ---------------- precompute kernels ----------------

__global__ void k_build(const float* __restrict__ feat, int* __restrict__ head,
                        int* __restrict__ nxt, int* __restrict__ cellxy) {
    int gid = blockIdx.x * 256 + threadIdx.x;
    if (gid >= NEV) return;
    int b = gid >> 6, t = gid & 63;
    int base = (b * Tc + t) * 4;
    int gx = (int)feat[base + 2] + SWc;
    int gy = (int)feat[base + 3] + SWc;
    gx = min(max(gx, 0), NXc - 1);
    gy = min(max(gy, 0), NXc - 1);
    int cell = gx * NXc + gy;
    int e = t * Bc + b;
    cellxy[e] = (gx << 16) | gy;
    int old = atomicExch(&head[cell], e);
    nxt[e] = old;
}

__global__ void k_resolve(const int* __restrict__ head, const int* __restrict__ nxt,
                          const int* __restrict__ cellxy, int* __restrict__ dep) {
    int gid = blockIdx.x * 256 + threadIdx.x;
    if (gid >= NEV * 25) return;
    int r = gid / 25, k = gid - r * 25;
    int t = r & 63, b = r >> 6;
    int e0 = t * Bc + b;
    int xy = cellxy[e0];
    int gx = xy >> 16, gy = xy & 0xffff;
    int cx = gx + (k / 5) - SWc, cy = gy + (k % 5) - SWc;
    cx = min(max(cx, 0), NXc - 1);
    cy = min(max(cy, 0), NXc - 1);
    int cell = cx * NXc + cy;
    int best = -1;
    for (int e = head[cell]; e >= 0; e = nxt[e])
        if ((e >> 9) < t && e > best) best = e;
    dep[r * 25 + k] = best;
}

// ---------------- fast math ----------------

#define LOG2E 1.4426950408889634f
__device__ __forceinline__ float fexp(float x)  { return __builtin_amdgcn_exp2f(x * LOG2E); }
__device__ __forceinline__ float fsig(float x)  { return __builtin_amdgcn_rcpf(1.f + fexp(-x)); }
__device__ __forceinline__ float ftanh(float x) { return 1.f - 2.f * __builtin_amdgcn_rcpf(1.f + fexp(2.f * x)); }

// LDS-only barrier: waits lgkmcnt(0), leaves global ops in flight.
__device__ __forceinline__ void barlds() {
    asm volatile("" ::: "memory");
    __builtin_amdgcn_s_waitcnt(0xC07F);   // vmcnt=63, expcnt=7, lgkmcnt=0
    __builtin_amdgcn_s_barrier();
    asm volatile("" ::: "memory");
}

// ---------------- main persistent dataflow kernel ----------------

// LDS (floats-equivalent): WoutH half2[128][129] = 16512 + step buffers 5200
constexpr int LDS_FLOATS = 16512 + 256 + 1024 + 256 + 256 + 256 + 64 + 2048 + 512 + 16 + 128 + 256 + 128;
constexpr int LDS_BYTES  = LDS_FLOATS * 4;   // ~86.9 KB

__global__ void
__attribute__((amdgpu_flat_work_group_size(1024, 1024)))
__attribute__((amdgpu_waves_per_eu(4, 4)))
step_main(const float* __restrict__ feat, const float* __restrict__ Wih,
          const float* __restrict__ bih,  const float* __restrict__ Whh,
          const float* __restrict__ bhh,  const float* __restrict__ Wout,
          const float* __restrict__ bout, const int*   __restrict__ seq,
          const int*   __restrict__ dep,  float* __restrict__ vbuf,
          unsigned*    __restrict__ flags, float* __restrict__ dout) {
    extern __shared__ float lds[];
    __half2* WoutH = (__half2*)lds;          // [128][129] half2, +1 pad -> 2-way banks
    float* hid   = lds + 16512;              // 2*128
    float* g     = hid   + 256;              // 2*512 gate pre-acts (INTACT all step)
    float* gin   = g     + 1024;             // 2*128
    float* ctr   = gin   + 256;              // 2*128
    float* qvL   = ctr   + 256;              // 2*128
    float* scor  = qvL   + 256;              // 2*32
    float* pmix  = scor  + 64;               // 16*128
    float* catL  = pmix  + 2048;             // 2*256 cat=[mix,q]
    float* fxy   = catL  + 512;              // 2 parities * 8
    float* boutL = fxy   + 16;               // 128
    float* updL  = boutL + 128;              // 2*128 staged vbuf payload
    int*   depv  = (int*)(updL + 256);       // 2 parities * 64 (50 used)

    const int tid  = threadIdx.x;            // 0..1023
    const int blk  = blockIdx.x;
    const int lane = tid & 63;
    const int w    = tid >> 6;               // wave 0..15
    const int wj   = w >> 3;                 // chain of this wave
    const int ww   = w & 7;                  // wave-within-chain

    // ---- W_hh half-row per thread (64 regs; unified VGPR/AGPR file) ----
    const int o    = tid >> 1;
    const int half = tid & 1;
    float4 wr[16];                           // statically indexed only (rule #20)
    {
        const float4* wp = (const float4*)(Whh + (size_t)o * Hc + half * 64);
        #pragma unroll
        for (int i = 0; i < 16; ++i) wr[i] = wp[i];
    }
    #pragma unroll
    for (int i = 0; i < 16; ++i)
        asm volatile("" : "+v"(wr[i].x), "+v"(wr[i].y), "+v"(wr[i].z), "+v"(wr[i].w));

    const float bihr = bih[o], bhhr = bhh[o];
    const float wih0 = Wih[o * 2 + 0], wih1 = Wih[o * 2 + 1];
    const int chunk = o >> 7;

    // stage W_out as fp16 pairs, b_out, init
    for (int i = tid; i < 128 * 128; i += 1024) {
        int r = i >> 7, c2 = i & 127;
        WoutH[r * 129 + c2] = __floats2half2_rn(Wout[r * 256 + 2 * c2],
                                                Wout[r * 256 + 2 * c2 + 1]);
    }
    if (tid < 128) boutL[tid] = bout[tid];
    if (tid < 256) hid[tid] = 0.f;
    if (tid < 8) { int j = tid >> 2, c = tid & 3;
                   fxy[tid] = feat[((size_t)(blk * 2 + j) * Tc + 0) * 4 + c]; }
    if (tid < 50) {        // deps for t=0 (all -1 by construction, but load anyway)
        int j = (tid >= 25), k = tid - j * 25;
        depv[tid] = dep[(((size_t)(blk * 2 + j)) * Tc + 0) * 25 + k];
    }
    const int s0 = max(seq[blk * 2 + 0], 1) - 1;
    const int s1 = max(seq[blk * 2 + 1], 1) - 1;
    __syncthreads();

    const float NEG_INF = -__builtin_inff();

    for (int t = 0; t < Tc; ++t) {
        const float* fx = fxy + (t & 1) * 8;
        int* depvCur = depv + (t & 1) * 64;
        int* depvNxt = depv + ((t + 1) & 1) * 64;

        // ==== P1: publish(t-1) + flag prefetch + gh GEMV + next-dep/fxy loads ====
        if (t > 0 && (w == 0 || w == 2)) {       // wave 0 -> chain0, wave 2 -> chain1
            int j = w >> 1;
            float2 u = *(const float2*)&updL[j * 128 + 2 * lane];
            unsigned long long raw; __builtin_memcpy(&raw, &u, 8);
            __hip_atomic_store((unsigned long long*)(vbuf +
                ((size_t)((t - 1) * Bc + blk * 2 + j)) * Hc + 2 * lane),
                raw, __ATOMIC_RELAXED, __HIP_MEMORY_SCOPE_AGENT);
        }
        const int mye = (lane < 25) ? depvCur[wj * 25 + lane] : -1;
        unsigned fpre = 1u;
        if (mye >= 0)
            fpre = __hip_atomic_load(&flags[mye], __ATOMIC_RELAXED,
                                     __HIP_MEMORY_SCOPE_AGENT);

        float acc0j, acc1j;
        {
            const float4* hp0 = (const float4*)(hid + half * 64);
            const float4* hp1 = (const float4*)(hid + 128 + half * 64);
            float a0 = 0.f, a1 = 0.f, a2 = 0.f, a3 = 0.f;
            float b0 = 0.f, b1 = 0.f, b2 = 0.f, b3 = 0.f;
            #pragma unroll
            for (int i = 0; i < 16; ++i) {
                float4 w4 = wr[i];
                float4 h0 = hp0[i], h1 = hp1[i];
                a0 = fmaf(w4.x, h0.x, a0); a1 = fmaf(w4.y, h0.y, a1);
                a2 = fmaf(w4.z, h0.z, a2); a3 = fmaf(w4.w, h0.w, a3);
                b0 = fmaf(w4.x, h1.x, b0); b1 = fmaf(w4.y, h1.y, b1);
                b2 = fmaf(w4.z, h1.z, b2); b3 = fmaf(w4.w, h1.w, b3);
            }
            acc0j = (a0 + a1) + (a2 + a3);
            acc1j = (b0 + b1) + (b2 + b3);
        }
        acc0j += __shfl_xor(acc0j, 1, 64);
        acc1j += __shfl_xor(acc1j, 1, 64);
        if (half == 0) {
            float gi0 = fmaf(wih0, fx[0], wih1 * fx[1]);
            float gi1 = fmaf(wih0, fx[4], wih1 * fx[5]);
            g[o]       = acc0j + bhhr + ((chunk == 2) ? 0.f : (gi0 + bihr));
            g[512 + o] = acc1j + bhhr + ((chunk == 2) ? 0.f : (gi1 + bihr));
            if (chunk == 2) { gin[o & 127] = gi0 + bihr; gin[128 + (o & 127)] = gi1 + bihr; }
        }
        if (tid >= 512 && tid < 562 && t + 1 < Tc) {
            int idx = tid - 512;
            int j = (idx >= 25), k = idx - j * 25;
            depvNxt[idx] = dep[(((size_t)(blk * 2 + j)) * Tc + (t + 1)) * 25 + k];
        }
        if (tid >= 960 && tid < 968 && t + 1 < Tc) {
            int idx = tid - 960, j = idx >> 2, c = idx & 3;
            fxy[((t + 1) & 1) * 8 + idx] =
                feat[((size_t)(blk * 2 + j) * Tc + (t + 1)) * 4 + c];
        }
        if (t > 0 && (w == 0 || w == 2)) {       // ack arrived during GEMV -> ~free
            asm volatile("s_waitcnt vmcnt(0)" ::: "memory");
            if (lane == 0)
                __hip_atomic_store(&flags[(t - 1) * Bc + blk * 2 + (w >> 1)], 1u,
                                   __ATOMIC_RELAXED, __HIP_MEMORY_SCOPE_AGENT);
        }
        // check prefetched flags; spin only on fresh deps; then issue value loads
        {
            bool pend = (mye >= 0) && (fpre == 0u);
            while (__any(pend)) {
                if (pend && __hip_atomic_load(&flags[mye], __ATOMIC_RELAXED,
                                              __HIP_MEMORY_SCOPE_AGENT) != 0u)
                    pend = false;
                if (__any(pend)) __builtin_amdgcn_s_sleep(1);
            }
        }
        asm volatile("" ::: "memory");           // value loads strictly after flags
        float2 valk[4];
        int    evk[4];
        #pragma unroll
        for (int kk = 0; kk < 4; ++kk) {
            int k = ww + 8 * kk;
            evk[kk] = (k < 25) ? depvCur[wj * 25 + k] : -1;
            valk[kk] = make_float2(0.f, 0.f);
            if (evk[kk] >= 0)
                valk[kk] = *(const float2*)(vbuf + (size_t)evk[kk] * Hc + 2 * lane);
        }
        barlds();

        // ==== P4: per-wave q + ctr + scores ====
        float q0, q1;
        {
            float2 gr2 = *(const float2*)&g[wj * 512 + 2 * lane];
            float2 gn2 = *(const float2*)&g[wj * 512 + 256 + 2 * lane];
            float2 gi2 = *(const float2*)&gin[wj * 128 + 2 * lane];
            q0 = ftanh(gi2.x + fsig(gr2.x) * gn2.x);
            q1 = ftanh(gi2.y + fsig(gr2.y) * gn2.y);
        }
        if (ww == 0) *(float2*)&qvL[wj * 128 + 2 * lane] = make_float2(q0, q1);
        if (ww == 4)   // owns k=12 (kk=1): center context (0 if absent)
            *(float2*)&ctr[wj * 128 + 2 * lane] =
                (evk[1] >= 0) ? valk[1] : make_float2(0.f, 0.f);
        #pragma unroll
        for (int kk = 0; kk < 4; ++kk) {
            int k = ww + 8 * kk;
            if (k < 25) {
                float sc;
                if (evk[kk] >= 0) {
                    float d = fmaf(valk[kk].x, q0, valk[kk].y * q1);
                    #pragma unroll
                    for (int m = 1; m < 64; m <<= 1) d += __shfl_xor(d, m, 64);
                    sc = (d == 0.f) ? NEG_INF : d;
                } else sc = NEG_INF;
                if (lane == 0) scor[wj * 32 + k] = sc;
            }
        }
        barlds();

        // ==== P56: per-wave softmax (32-lane groups) + mix partials ====
        {
            int k2 = lane & 31;
            float v = (k2 < 25) ? scor[wj * 32 + k2] : NEG_INF;
            float m = v;
            #pragma unroll
            for (int mm = 1; mm < 32; mm <<= 1) m = fmaxf(m, __shfl_xor(m, mm, 64));
            float a = 0.f;
            if (m != NEG_INF) {
                float p = (v == NEG_INF) ? 0.f : fexp(v - m);
                float s = p;
                #pragma unroll
                for (int mm = 1; mm < 32; mm <<= 1) s += __shfl_xor(s, mm, 64);
                a = p / s;
            }
            float pm0 = 0.f, pm1 = 0.f;
            #pragma unroll
            for (int kk = 0; kk < 4; ++kk) {
                int k = ww + 8 * kk;
                if (k < 25 && evk[kk] >= 0) {
                    float ak = __shfl(a, k, 64);
                    pm0 = fmaf(ak, valk[kk].x, pm0);
                    pm1 = fmaf(ak, valk[kk].y, pm1);
                }
            }
            *(float2*)&pmix[(wj * 8 + ww) * 128 + 2 * lane] = make_float2(pm0, pm1);
        }
        barlds();

        // ==== P7a: cat = [mix, q] into catL (g stays intact) ====
        if (tid < 256) {
            int j = tid >> 7, h = tid & 127;
            float mix = 0.f;
            #pragma unroll
            for (int p = 0; p < 8; ++p) mix += pmix[(j * 8 + p) * 128 + h];
            catL[j * 256 + h] = mix;
            catL[j * 256 + 128 + h] = qvL[j * 128 + h];
        }
        barlds();

        // ==== P7b: W_out dots (fp16 weights, stride-129 half2, 2-way banks) ====
        {
            int oo = tid & 127, rep = tid >> 7;
            const __half2* wrow = WoutH + oo * 129 + rep * 16;
            const float4* c04 = (const float4*)(catL + rep * 32);
            const float4* c14 = (const float4*)(catL + 256 + rep * 32);
            float acc0 = 0.f, acc1 = 0.f;
            #pragma unroll
            for (int i = 0; i < 8; ++i) {
                __half2 wa = wrow[2 * i], wb = wrow[2 * i + 1];
                float wx = __low2float(wa), wy = __high2float(wa);
                float wz = __low2float(wb), wwv = __high2float(wb);
                float4 c0 = c04[i], c1 = c14[i];
                acc0 = fmaf(wx, c0.x, fmaf(wy, c0.y, fmaf(wz, c0.z, fmaf(wwv, c0.w, acc0))));
                acc1 = fmaf(wx, c1.x, fmaf(wy, c1.y, fmaf(wz, c1.z, fmaf(wwv, c1.w, acc1))));
            }
            pmix[rep * 128 + oo]       = acc0;
            pmix[(8 + rep) * 128 + oo] = acc1;
        }
        barlds();

        // ==== P7c: epilogue (full gate recompute from intact g) ====
        if (tid < 256) {
            int j = tid >> 7, h = tid & 127;
            float tot = boutL[h];
            #pragma unroll
            for (int p = 0; p < 8; ++p) tot += pmix[(j * 8 + p) * 128 + h];
            float at = ftanh(tot);
            float gr = g[j * 512 + h],       gu = g[j * 512 + 128 + h];
            float gn = g[j * 512 + 256 + h], gs = g[j * 512 + 384 + h];
            float rr = fsig(gr), uu = fsig(gu), ss = fsig(gs);
            float nn = ftanh(gin[j * 128 + h] + rr * gn);
            float hv = hid[j * 128 + h];
            float curr = fmaf(ss, at, nn);
            float outv = curr + uu * (hv - curr);
            hid[j * 128 + h] = outv;
            if (t < Tc - 1)
                updL[tid] = fmaf(ss, ctr[j * 128 + h], (1.f - ss) * outv);
            int sj = (j == 0) ? s0 : s1;
            if (sj == t) dout[(size_t)(blk * 2 + j) * Hc + h] = outv;
        }
        barlds();
    }
}

// ---------------- host launch ----------------

extern "C" void kernel_launch(void* const* d_in, const int* in_sizes, int n_in,
                              void* d_out, int out_size, void* d_ws, size_t ws_size,
                              hipStream_t stream) {
    const float* feat = (const float*)d_in[0];
    const float* Wih  = (const float*)d_in[1];
    const float* bih  = (const float*)d_in[2];
    const float* Whh  = (const float*)d_in[3];
    const float* bhh  = (const float*)d_in[4];
    const float* Wout = (const float*)d_in[5];
    const float* bout = (const float*)d_in[6];
    const int*   seq  = (const int*)d_in[7];

    char* ws = (char*)d_ws;
    size_t off = 0;
    auto carve = [&](size_t bytes) { char* p = ws + off; off += (bytes + 511) & ~(size_t)511; return p; };
    float*    vbuf   = (float*)   carve((size_t)NEV * Hc * 4);
    int*      head   = (int*)     carve((size_t)NCELL * 4);
    int*      nxt    = (int*)     carve((size_t)NEV * 4);
    int*      cellxy = (int*)     carve((size_t)NEV * 4);
    int*      dep    = (int*)     carve((size_t)NEV * 25 * 4);
    unsigned* flags  = (unsigned*)carve((size_t)NEV * 4);

    hipMemsetAsync(head, 0xFF, (size_t)NCELL * 4, stream);
    hipMemsetAsync(flags, 0, (size_t)NEV * 4, stream);

    k_build<<<(NEV + 255) / 256, 256, 0, stream>>>(feat, head, nxt, cellxy);
    k_resolve<<<(NEV * 25 + 255) / 256, 256, 0, stream>>>(head, nxt, cellxy, dep);

    hipFuncSetAttribute((const void*)step_main,
                        hipFuncAttributeMaxDynamicSharedMemorySize, LDS_BYTES);
    step_main<<<256, 1024, LDS_BYTES, stream>>>(feat, Wih, bih, Whh, bhh, Wout, bout,
                                                seq, dep, vbuf, flags, (float*)d_out);
}

// Round 11
// 459.084 us; speedup vs baseline: 1.4094x; 1.1234x over previous
//
#include <hip/hip_runtime.h>
#include <hip/hip_fp16.h>
#include <math.h>

#define Hc   128
#define Bc   512
#define Tc   64
#define NXc  518
#define NCELL (518*518)
#define NEV  (Bc*Tc)            // 32768 events
#define SWc  2

// ---------------- precompute kernels ----------------

__global__ void k_build(const float* __restrict__ feat, int* __restrict__ head,
                        int* __restrict__ nxt, int* __restrict__ cellxy) {
    int gid = blockIdx.x * 256 + threadIdx.x;
    if (gid >= NEV) return;
    int b = gid >> 6, t = gid & 63;
    int base = (b * Tc + t) * 4;
    int gx = (int)feat[base + 2] + SWc;
    int gy = (int)feat[base + 3] + SWc;
    gx = min(max(gx, 0), NXc - 1);
    gy = min(max(gy, 0), NXc - 1);
    int cell = gx * NXc + gy;
    int e = t * Bc + b;
    cellxy[e] = (gx << 16) | gy;
    int old = atomicExch(&head[cell], e);
    nxt[e] = old;
}

__global__ void k_resolve(const int* __restrict__ head, const int* __restrict__ nxt,
                          const int* __restrict__ cellxy, int* __restrict__ dep) {
    int gid = blockIdx.x * 256 + threadIdx.x;
    if (gid >= NEV * 25) return;
    int r = gid / 25, k = gid - r * 25;
    int t = r & 63, b = r >> 6;
    int e0 = t * Bc + b;
    int xy = cellxy[e0];
    int gx = xy >> 16, gy = xy & 0xffff;
    int cx = gx + (k / 5) - SWc, cy = gy + (k % 5) - SWc;
    cx = min(max(cx, 0), NXc - 1);
    cy = min(max(cy, 0), NXc - 1);
    int cell = cx * NXc + cy;
    int best = -1;
    for (int e = head[cell]; e >= 0; e = nxt[e])
        if ((e >> 9) < t && e > best) best = e;
    dep[r * 25 + k] = best;
}

// ---------------- fast math + cross-lane (VALU where possible) ----------------

#define LOG2E 1.4426950408889634f
__device__ __forceinline__ float fexp(float x)  { return __builtin_amdgcn_exp2f(x * LOG2E); }
__device__ __forceinline__ float fsig(float x)  { return __builtin_amdgcn_rcpf(1.f + fexp(-x)); }
__device__ __forceinline__ float ftanh(float x) { return 1.f - 2.f * __builtin_amdgcn_rcpf(1.f + fexp(2.f * x)); }

// DPP cross-lane adds/maxes (VALU pipe — zero LDS). Ctrl: 0xB1 quad xor1,
// 0x4E quad xor2, 0x141 ROW_HALF_MIRROR (xor4-equiv after quad-uniform),
// 0x140 ROW_MIRROR (xor8-equiv after 8-uniform).
template <int CTRL>
__device__ __forceinline__ float dppadd(float x) {
    int t = __builtin_amdgcn_update_dpp(0, __float_as_int(x), CTRL, 0xF, 0xF, true);
    return x + __int_as_float(t);
}
template <int CTRL>
__device__ __forceinline__ float dppmax(float x) {
    int t = __builtin_amdgcn_update_dpp(0, __float_as_int(x), CTRL, 0xF, 0xF, true);
    return fmaxf(x, __int_as_float(t));
}
__device__ __forceinline__ float swz16(float x) {   // lane ^= 16 within 32-groups
    return __int_as_float(__builtin_amdgcn_ds_swizzle(__float_as_int(x), 0x401F));
}
// full 64-lane sum: 4 DPP + 1 swizzle + 1 bpermute
__device__ __forceinline__ float redsum64(float d) {
    d = dppadd<0xB1>(d); d = dppadd<0x4E>(d);
    d = dppadd<0x141>(d); d = dppadd<0x140>(d);
    d += swz16(d);
    d += __shfl_xor(d, 32, 64);
    return d;
}

// LDS-only barrier: waits lgkmcnt(0), leaves global ops in flight.
__device__ __forceinline__ void barlds() {
    asm volatile("" ::: "memory");
    __builtin_amdgcn_s_waitcnt(0xC07F);   // vmcnt=63, expcnt=7, lgkmcnt=0
    __builtin_amdgcn_s_barrier();
    asm volatile("" ::: "memory");
}

// ---------------- main persistent dataflow kernel ----------------

constexpr int LDS_FLOATS = 16512 + 256 + 1024 + 256 + 256 + 256 + 64 + 2048 + 512 + 16 + 128 + 256 + 128;
constexpr int LDS_BYTES  = LDS_FLOATS * 4;   // ~86.9 KB

__global__ void
__attribute__((amdgpu_flat_work_group_size(1024, 1024)))
__attribute__((amdgpu_waves_per_eu(4, 4)))
step_main(const float* __restrict__ feat, const float* __restrict__ Wih,
          const float* __restrict__ bih,  const float* __restrict__ Whh,
          const float* __restrict__ bhh,  const float* __restrict__ Wout,
          const float* __restrict__ bout, const int*   __restrict__ seq,
          const int*   __restrict__ dep,  float* __restrict__ vbuf,
          unsigned*    __restrict__ flags, float* __restrict__ dout) {
    extern __shared__ float lds[];
    __half2* WoutH = (__half2*)lds;          // [128][129] half2
    float* hid   = lds + 16512;              // 2*128
    float* g     = hid   + 256;              // 2*512 gate pre-acts (INTACT all step)
    float* gin   = g     + 1024;             // 2*128
    float* ctr   = gin   + 256;              // 2*128
    float* qvL   = ctr   + 256;              // 2*128
    float* scor  = qvL   + 256;              // 2*32
    float* pmix  = scor  + 64;               // 16*128
    float* catL  = pmix  + 2048;             // 2*256 cat=[mix,q]
    float* fxy   = catL  + 512;              // 2 parities * 8
    float* boutL = fxy   + 16;               // 128
    float* updL  = boutL + 128;              // 2*128 staged vbuf payload
    int*   depv  = (int*)(updL + 256);       // 2 parities * 64 (50 used)

    const int tid  = threadIdx.x;            // 0..1023
    const int blk  = blockIdx.x;
    const int lane = tid & 63;
    const int w    = tid >> 6;               // wave 0..15
    const int wj   = w >> 3;                 // chain of this wave
    const int ww   = w & 7;                  // wave-within-chain

    // ---- W_hh: 2 rows x 32 interleaved cols per thread (64 regs) ----
    const int rp = tid >> 2;                 // row pair: rows 2rp, 2rp+1
    const int q  = tid & 3;                  // col slice (interleaved float4s)
    const int r0 = 2 * rp, r1 = 2 * rp + 1;
    float4 wr0[8], wr1[8];                   // statically indexed only (rule #20)
    {
        const float4* w0 = (const float4*)(Whh + (size_t)r0 * Hc);
        const float4* w1 = (const float4*)(Whh + (size_t)r1 * Hc);
        #pragma unroll
        for (int i = 0; i < 8; ++i) { wr0[i] = w0[q + 4 * i]; wr1[i] = w1[q + 4 * i]; }
    }
    #pragma unroll
    for (int i = 0; i < 8; ++i) {
        asm volatile("" : "+v"(wr0[i].x), "+v"(wr0[i].y), "+v"(wr0[i].z), "+v"(wr0[i].w));
        asm volatile("" : "+v"(wr1[i].x), "+v"(wr1[i].y), "+v"(wr1[i].z), "+v"(wr1[i].w));
    }
    // write-assignment: this thread publishes g[jw*512 + rw]
    const int jw = q & 1;
    const int rw = r0 + (q >> 1);
    const float bihr = bih[rw], bhhr = bhh[rw];
    const float wihA = Wih[rw * 2 + 0], wihB = Wih[rw * 2 + 1];
    const int chunk = rw >> 7;

    // stage W_out as fp16 pairs, b_out, init
    for (int i = tid; i < 128 * 128; i += 1024) {
        int r = i >> 7, c2 = i & 127;
        WoutH[r * 129 + c2] = __floats2half2_rn(Wout[r * 256 + 2 * c2],
                                                Wout[r * 256 + 2 * c2 + 1]);
    }
    if (tid < 128) boutL[tid] = bout[tid];
    if (tid < 256) hid[tid] = 0.f;
    if (tid < 8) { int j = tid >> 2, c = tid & 3;
                   fxy[tid] = feat[((size_t)(blk * 2 + j) * Tc + 0) * 4 + c]; }
    if (tid < 50) {
        int j = (tid >= 25), k = tid - j * 25;
        depv[tid] = dep[(((size_t)(blk * 2 + j)) * Tc + 0) * 25 + k];
    }
    const int s0 = max(seq[blk * 2 + 0], 1) - 1;
    const int s1 = max(seq[blk * 2 + 1], 1) - 1;
    __syncthreads();

    const float NEG_INF = -__builtin_inff();

    for (int t = 0; t < Tc; ++t) {
        const float* fx = fxy + (t & 1) * 8;
        int* depvCur = depv + (t & 1) * 64;
        int* depvNxt = depv + ((t + 1) & 1) * 64;

        // ==== P1: publish(t-1) + flag prefetch + gh GEMV + next-dep/fxy loads ====
        if (t > 0 && (w == 0 || w == 2)) {
            int j = w >> 1;
            float2 u = *(const float2*)&updL[j * 128 + 2 * lane];
            unsigned long long raw; __builtin_memcpy(&raw, &u, 8);
            __hip_atomic_store((unsigned long long*)(vbuf +
                ((size_t)((t - 1) * Bc + blk * 2 + j)) * Hc + 2 * lane),
                raw, __ATOMIC_RELAXED, __HIP_MEMORY_SCOPE_AGENT);
        }
        const int mye = (lane < 25) ? depvCur[wj * 25 + lane] : -1;
        unsigned fpre = 1u;
        if (mye >= 0)
            fpre = __hip_atomic_load(&flags[mye], __ATOMIC_RELAXED,
                                     __HIP_MEMORY_SCOPE_AGENT);

        // 2-row x 32-col GEMV: each h float4 feeds 4 FMAs
        float a00 = 0.f, a01 = 0.f, a10 = 0.f, a11 = 0.f;   // a[chain][row]
        {
            const float4* h0 = (const float4*)hid;
            const float4* h1 = (const float4*)(hid + 128);
            #pragma unroll
            for (int i = 0; i < 8; ++i) {
                float4 hv0 = h0[q + 4 * i], hv1 = h1[q + 4 * i];
                float4 w0 = wr0[i], w1 = wr1[i];
                a00 = fmaf(w0.x, hv0.x, fmaf(w0.y, hv0.y, fmaf(w0.z, hv0.z, fmaf(w0.w, hv0.w, a00))));
                a01 = fmaf(w1.x, hv0.x, fmaf(w1.y, hv0.y, fmaf(w1.z, hv0.z, fmaf(w1.w, hv0.w, a01))));
                a10 = fmaf(w0.x, hv1.x, fmaf(w0.y, hv1.y, fmaf(w0.z, hv1.z, fmaf(w0.w, hv1.w, a10))));
                a11 = fmaf(w1.x, hv1.x, fmaf(w1.y, hv1.y, fmaf(w1.z, hv1.z, fmaf(w1.w, hv1.w, a11))));
            }
        }
        // quad reduce (DPP, VALU) then pick this thread's (jw, rw)
        a00 = dppadd<0x4E>(dppadd<0xB1>(a00));
        a01 = dppadd<0x4E>(dppadd<0xB1>(a01));
        a10 = dppadd<0x4E>(dppadd<0xB1>(a10));
        a11 = dppadd<0x4E>(dppadd<0xB1>(a11));
        {
            float mine = (q & 1) ? ((q >> 1) ? a11 : a10) : ((q >> 1) ? a01 : a00);
            float gi  = fmaf(wihA, fx[jw * 4 + 0], wihB * fx[jw * 4 + 1]);
            g[jw * 512 + rw] = mine + bhhr + ((chunk == 2) ? 0.f : (gi + bihr));
            if (chunk == 2) gin[jw * 128 + (rw & 127)] = gi + bihr;
        }
        if (tid >= 512 && tid < 562 && t + 1 < Tc) {
            int idx = tid - 512;
            int j = (idx >= 25), k = idx - j * 25;
            depvNxt[idx] = dep[(((size_t)(blk * 2 + j)) * Tc + (t + 1)) * 25 + k];
        }
        if (tid >= 960 && tid < 968 && t + 1 < Tc) {
            int idx = tid - 960, j = idx >> 2, c = idx & 3;
            fxy[((t + 1) & 1) * 8 + idx] =
                feat[((size_t)(blk * 2 + j) * Tc + (t + 1)) * 4 + c];
        }
        if (t > 0 && (w == 0 || w == 2)) {
            asm volatile("s_waitcnt vmcnt(0)" ::: "memory");
            if (lane == 0)
                __hip_atomic_store(&flags[(t - 1) * Bc + blk * 2 + (w >> 1)], 1u,
                                   __ATOMIC_RELAXED, __HIP_MEMORY_SCOPE_AGENT);
        }
        {
            bool pend = (mye >= 0) && (fpre == 0u);
            while (__any(pend)) {
                if (pend && __hip_atomic_load(&flags[mye], __ATOMIC_RELAXED,
                                              __HIP_MEMORY_SCOPE_AGENT) != 0u)
                    pend = false;
                if (__any(pend)) __builtin_amdgcn_s_sleep(1);
            }
        }
        asm volatile("" ::: "memory");
        float2 valk[4];
        int    evk[4];
        #pragma unroll
        for (int kk = 0; kk < 4; ++kk) {
            int k = ww + 8 * kk;
            evk[kk] = (k < 25) ? depvCur[wj * 25 + k] : -1;
            valk[kk] = make_float2(0.f, 0.f);
            if (evk[kk] >= 0)
                valk[kk] = *(const float2*)(vbuf + (size_t)evk[kk] * Hc + 2 * lane);
        }
        barlds();

        // ==== P4: per-wave q + ctr + scores (DPP reduce) ====
        float q0, q1;
        {
            float2 gr2 = *(const float2*)&g[wj * 512 + 2 * lane];
            float2 gn2 = *(const float2*)&g[wj * 512 + 256 + 2 * lane];
            float2 gi2 = *(const float2*)&gin[wj * 128 + 2 * lane];
            q0 = ftanh(gi2.x + fsig(gr2.x) * gn2.x);
            q1 = ftanh(gi2.y + fsig(gr2.y) * gn2.y);
        }
        if (ww == 0) *(float2*)&qvL[wj * 128 + 2 * lane] = make_float2(q0, q1);
        if (ww == 4)
            *(float2*)&ctr[wj * 128 + 2 * lane] =
                (evk[1] >= 0) ? valk[1] : make_float2(0.f, 0.f);
        #pragma unroll
        for (int kk = 0; kk < 4; ++kk) {
            int k = ww + 8 * kk;
            if (k < 25) {
                float sc;
                if (evk[kk] >= 0) {
                    float d = fmaf(valk[kk].x, q0, valk[kk].y * q1);
                    d = redsum64(d);
                    sc = (d == 0.f) ? NEG_INF : d;
                } else sc = NEG_INF;
                if (lane == 0) scor[wj * 32 + k] = sc;
            }
        }
        barlds();

        // ==== P56: per-wave softmax (32-lane groups, DPP) + mix partials ====
        {
            int k2 = lane & 31;
            float v = (k2 < 25) ? scor[wj * 32 + k2] : NEG_INF;
            float m = v;
            m = dppmax<0xB1>(m); m = dppmax<0x4E>(m);
            m = dppmax<0x141>(m); m = dppmax<0x140>(m);
            m = fmaxf(m, swz16(m));
            float a = 0.f;
            if (m != NEG_INF) {
                float p = (v == NEG_INF) ? 0.f : fexp(v - m);
                float s = p;
                s = dppadd<0xB1>(s); s = dppadd<0x4E>(s);
                s = dppadd<0x141>(s); s = dppadd<0x140>(s);
                s += swz16(s);
                a = p / s;
            }
            float pm0 = 0.f, pm1 = 0.f;
            #pragma unroll
            for (int kk = 0; kk < 4; ++kk) {
                int k = ww + 8 * kk;
                if (k < 25 && evk[kk] >= 0) {
                    float ak = __int_as_float(
                        __builtin_amdgcn_readlane(__float_as_int(a), k));
                    pm0 = fmaf(ak, valk[kk].x, pm0);
                    pm1 = fmaf(ak, valk[kk].y, pm1);
                }
            }
            *(float2*)&pmix[(wj * 8 + ww) * 128 + 2 * lane] = make_float2(pm0, pm1);
        }
        barlds();

        // ==== P7a: cat = [mix, q] into catL ====
        if (tid < 256) {
            int j = tid >> 7, h = tid & 127;
            float mix = 0.f;
            #pragma unroll
            for (int p = 0; p < 8; ++p) mix += pmix[(j * 8 + p) * 128 + h];
            catL[j * 256 + h] = mix;
            catL[j * 256 + 128 + h] = qvL[j * 128 + h];
        }
        barlds();

        // ==== P7b: W_out dots (fp16 weights stride-129; uniform b128 cat) ====
        {
            int oo = tid & 127, rep = tid >> 7;
            const __half2* wrow = WoutH + oo * 129 + rep * 16;
            const float4* c04 = (const float4*)(catL + rep * 32);
            const float4* c14 = (const float4*)(catL + 256 + rep * 32);
            float acc0 = 0.f, acc1 = 0.f;
            #pragma unroll
            for (int i = 0; i < 8; ++i) {
                __half2 wa = wrow[2 * i], wb = wrow[2 * i + 1];
                float wx = __low2float(wa), wy = __high2float(wa);
                float wz = __low2float(wb), wwv = __high2float(wb);
                float4 c0 = c04[i], c1 = c14[i];
                acc0 = fmaf(wx, c0.x, fmaf(wy, c0.y, fmaf(wz, c0.z, fmaf(wwv, c0.w, acc0))));
                acc1 = fmaf(wx, c1.x, fmaf(wy, c1.y, fmaf(wz, c1.z, fmaf(wwv, c1.w, acc1))));
            }
            pmix[rep * 128 + oo]       = acc0;
            pmix[(8 + rep) * 128 + oo] = acc1;
        }
        barlds();

        // ==== P7c: epilogue (full gate recompute from intact g) ====
        if (tid < 256) {
            int j = tid >> 7, h = tid & 127;
            float tot = boutL[h];
            #pragma unroll
            for (int p = 0; p < 8; ++p) tot += pmix[(j * 8 + p) * 128 + h];
            float at = ftanh(tot);
            float gr = g[j * 512 + h],       gu = g[j * 512 + 128 + h];
            float gn = g[j * 512 + 256 + h], gs = g[j * 512 + 384 + h];
            float rr = fsig(gr), uu = fsig(gu), ss = fsig(gs);
            float nn = ftanh(gin[j * 128 + h] + rr * gn);
            float hv = hid[j * 128 + h];
            float curr = fmaf(ss, at, nn);
            float outv = curr + uu * (hv - curr);
            hid[j * 128 + h] = outv;
            if (t < Tc - 1)
                updL[tid] = fmaf(ss, ctr[j * 128 + h], (1.f - ss) * outv);
            int sj = (j == 0) ? s0 : s1;
            if (sj == t) dout[(size_t)(blk * 2 + j) * Hc + h] = outv;
        }
        barlds();
    }
}

// ---------------- host launch ----------------

extern "C" void kernel_launch(void* const* d_in, const int* in_sizes, int n_in,
                              void* d_out, int out_size, void* d_ws, size_t ws_size,
                              hipStream_t stream) {
    const float* feat = (const float*)d_in[0];
    const float* Wih  = (const float*)d_in[1];
    const float* bih  = (const float*)d_in[2];
    const float* Whh  = (const float*)d_in[3];
    const float* bhh  = (const float*)d_in[4];
    const float* Wout = (const float*)d_in[5];
    const float* bout = (const float*)d_in[6];
    const int*   seq  = (const int*)d_in[7];

    char* ws = (char*)d_ws;
    size_t off = 0;
    auto carve = [&](size_t bytes) { char* p = ws + off; off += (bytes + 511) & ~(size_t)511; return p; };
    float*    vbuf   = (float*)   carve((size_t)NEV * Hc * 4);
    int*      head   = (int*)     carve((size_t)NCELL * 4);
    int*      nxt    = (int*)     carve((size_t)NEV * 4);
    int*      cellxy = (int*)     carve((size_t)NEV * 4);
    int*      dep    = (int*)     carve((size_t)NEV * 25 * 4);
    unsigned* flags  = (unsigned*)carve((size_t)NEV * 4);

    hipMemsetAsync(head, 0xFF, (size_t)NCELL * 4, stream);
    hipMemsetAsync(flags, 0, (size_t)NEV * 4, stream);

    k_build<<<(NEV + 255) / 256, 256, 0, stream>>>(feat, head, nxt, cellxy);
    k_resolve<<<(NEV * 25 + 255) / 256, 256, 0, stream>>>(head, nxt, cellxy, dep);

    hipFuncSetAttribute((const void*)step_main,
                        hipFuncAttributeMaxDynamicSharedMemorySize, LDS_BYTES);
    step_main<<<256, 1024, LDS_BYTES, stream>>>(feat, Wih, bih, Whh, bhh, Wout, bout,
                                                seq, dep, vbuf, flags, (float*)d_out);
}